// Round 4
// baseline (192.234 us; speedup 1.0000x reference)
//
#include <hip/hip_runtime.h>
#include <hip/hip_fp16.h>
#include <cstdint>

#define N_NODES 50000
#define N_EDGES 800000
#define N_FEAT 256
#define HIDDEN 128
#define N_CLASSES 40
#define NBUCKET 196         // dst >> 8
#define EPB 3125            // edges per partition block (256 * 3125 = 800000)
#define BCAP 8192           // bucket capacity in ebuf (max count ~4400)
#define ROWS_PAD 50048      // 782 * 64
#define G1_BLOCKS 782       // ROWS_PAD / 64
#define H2S 64              // h2 row stride (halves) = 128 B ALIGNED rows (2 cache lines/gather)

typedef _Float16 half8 __attribute__((ext_vector_type(8)));
typedef __fp16 fp16x2 __attribute__((ext_vector_type(2)));
typedef __attribute__((ext_vector_type(4))) float f32x4;
typedef __attribute__((ext_vector_type(2))) float f32x2;

__device__ inline ushort f2h(float f) {
    return __half_as_ushort(__float2half_rn(f));
}
__device__ inline float h2f_u(uint us) {
    union { ushort u; __half h; } v; v.u = (ushort)us; return __half2float(v.h);
}
__device__ inline __half2 u2h2(uint u) {
    union { uint u; __half2 h; } v; v.u = u; return v.h;
}
// replicate high half of u into both halves (agg2 weight rebuild)
__device__ inline uint wrep(uint u) {
    uint t = u >> 16;
    return (t << 16) | t;
}
// packed 2xf32 fma (compiler emits v_pk_fma_f32)
__device__ inline f32x2 pkfma(f32x2 a, f32x2 w, f32x2 c) {
    f32x2 r;
    r.x = __builtin_fmaf(a.x, w.x, c.x);
    r.y = __builtin_fmaf(a.y, w.y, c.y);
    return r;
}

// ---------------- 1) partition edges into fixed-capacity buckets + W1/W2 repack ----------------
// NO global per-node atomics (round-2 lesson: 800k random global atomicAdd = +26us).

__global__ __launch_bounds__(256) void partition_repack(
        const int* __restrict__ src, const int* __restrict__ dst,
        int* __restrict__ cursor, uint* __restrict__ ebuf,
        const float* __restrict__ W1, ushort* __restrict__ Bp1,
        const float* __restrict__ W2, ushort* __restrict__ Bp2) {
    __shared__ int h[NBUCKET];
    __shared__ int base[NBUCKET];
    __shared__ int cur[NBUCKET];
    int blk = blockIdx.x, t = threadIdx.x;
    int gid = blk * 256 + t;
    if (gid < 32768) {       // W1 repack into MFMA B-frag order (f16)
        int j = gid & 7, lane = (gid >> 3) & 63, kt = (gid >> 9) & 7, nt = gid >> 12;
        int k = kt * 32 + (lane >> 4) * 8 + j;
        int n = nt * 16 + (lane & 15);
        Bp1[gid] = f2h(W1[k * HIDDEN + n]);
    } else if (gid < 32768 + 6144) {   // W2 repack (3 nt * 4 kt * 64 * 8)
        int i2 = gid - 32768;
        int j = i2 & 7, lane = (i2 >> 3) & 63, kt = (i2 >> 9) & 3, nt = i2 >> 11;
        int k = kt * 32 + (lane >> 4) * 8 + j;
        int n = nt * 16 + (lane & 15);
        Bp2[i2] = (n < N_CLASSES) ? f2h(W2[k * N_CLASSES + n]) : (ushort)0;
    }
    if (t < NBUCKET) { h[t] = 0; cur[t] = 0; }
    __syncthreads();
    int eb = blk * EPB;
    for (int i = t; i < EPB; i += 256)
        atomicAdd(&h[dst[eb + i] >> 8], 1);
    __syncthreads();
    if (t < NBUCKET)
        base[t] = (h[t] > 0) ? atomicAdd(&cursor[t], h[t]) : 0;
    __syncthreads();
    for (int i = t; i < EPB; i += 256) {
        int d = dst[eb + i], sv = src[eb + i];
        int bk = d >> 8;
        int p = base[bk] + atomicAdd(&cur[bk], 1);
        ebuf[bk * BCAP + p] = ((uint)d << 16) | (uint)sv;
    }
}

// ---------------- 2) FUSED: bucket CSR build (blocks 0..195)  ||  GEMM1 (blocks 196..977) ----------
// GEMM1 now stores h1 as fp8 e4m3 (HW cvt) -> 128 B rows: halves agg1 gather traffic.

__global__ __launch_bounds__(256) void csr_gemm1(
        const uint* __restrict__ ebuf, const int* __restrict__ cursor,
        int* __restrict__ deg, float* __restrict__ dinv,
        int* __restrict__ rowptr, int* __restrict__ esrc,
        const float* __restrict__ x, const ushort* __restrict__ Bp,
        unsigned char* __restrict__ h1q) {
    if (blockIdx.x < NBUCKET) {
        // ----- per-bucket: degree + dinv + rowptr + CSR fill -----
        __shared__ int s[256];
        __shared__ int cnt[256];
        __shared__ int exc[256];
        __shared__ int cur[256];
        int b = blockIdx.x, t = threadIdx.x;
        s[t] = (t < NBUCKET) ? cursor[t] : 0;
        __syncthreads();
        for (int off = 1; off < 256; off <<= 1) {
            int t2 = 0;
            if (t >= off) t2 = s[t - off];
            __syncthreads();
            s[t] += t2;
            __syncthreads();
        }
        int beg = (b > 0) ? s[b - 1] : 0;      // CSR start of bucket b
        int ecnt = s[b] - beg;                 // edges in bucket b
        __syncthreads();
        cnt[t] = 0;
        cur[t] = 0;
        __syncthreads();
        const uint* eb = ebuf + (size_t)b * BCAP;
        for (int i = t; i < ecnt; i += 256)
            atomicAdd(&cnt[(eb[i] >> 16) & 255], 1);
        __syncthreads();
        int d = cnt[t];
        s[t] = d;
        __syncthreads();
        for (int off = 1; off < 256; off <<= 1) {
            int t2 = 0;
            if (t >= off) t2 = s[t - off];
            __syncthreads();
            s[t] += t2;
            __syncthreads();
        }
        exc[t] = s[t] - d;
        int node = b * 256 + t;
        if (node < N_NODES) {
            deg[node] = d;
            dinv[node] = rsqrtf((float)(d + 1));   // +1 self-loop
            rowptr[node] = beg + exc[t];
        }
        __syncthreads();
        for (int i = t; i < ecnt; i += 256) {
            uint u = eb[i];
            int dl = (int)(u >> 16) & 255;
            int pos = beg + exc[dl] + atomicAdd(&cur[dl], 1);
            esrc[pos] = (int)(u & 0xffffu);
        }
    } else {
        // ----- GEMM1: h1q[N,128] = fp8(f16(x[N,256]) @ W1)  (MFMA f16, no LDS) -----
        int t = threadIdx.x;
        int lane = t & 63, w = t >> 6;
        int r = lane & 15, q = lane >> 4;
        int row0 = (blockIdx.x - NBUCKET) * 64;
        int arow = row0 + w * 16 + r;
        if (arow >= N_NODES) arow = N_NODES - 1;     // clamp: no fault, row discarded later
        const float* xrow = x + (size_t)arow * N_FEAT;
        f32x4 acc[8] = {};
        for (int kt = 0; kt < 8; ++kt) {
            float4 v0 = *(const float4*)(xrow + kt * 32 + q * 8);
            float4 v1 = *(const float4*)(xrow + kt * 32 + q * 8 + 4);
            union { fp16x2 p[4]; half8 a; } u;
            u.p[0] = __builtin_amdgcn_cvt_pkrtz(v0.x, v0.y);
            u.p[1] = __builtin_amdgcn_cvt_pkrtz(v0.z, v0.w);
            u.p[2] = __builtin_amdgcn_cvt_pkrtz(v1.x, v1.y);
            u.p[3] = __builtin_amdgcn_cvt_pkrtz(v1.z, v1.w);
#pragma unroll
            for (int nt = 0; nt < 8; ++nt) {
                half8 b = *(const half8*)(Bp + (((nt * 8 + kt) * 64) + lane) * 8);
                acc[nt] = __builtin_amdgcn_mfma_f32_16x16x32_f16(u.a, b, acc[nt], 0, 0, 0);
            }
        }
#pragma unroll
        for (int nt = 0; nt < 8; ++nt) {
            int col = nt * 16 + r;
#pragma unroll
            for (int reg = 0; reg < 4; ++reg) {
                int row = row0 + w * 16 + q * 4 + reg;
                if (row < N_NODES) {
                    int enc = __builtin_amdgcn_cvt_pk_fp8_f32(acc[nt][reg], acc[nt][reg], 0, false);
                    h1q[(size_t)row * 128 + col] = (unsigned char)(enc & 0xff);
                }
            }
        }
    }
}

// ---------------- layer-1 aggregation (fp8 gather, f32 packed accum) FUSED with GEMM2 ----------

__global__ __launch_bounds__(256) void agg1_w2(
        const int* __restrict__ rowptr, const int* __restrict__ deg,
        const int* __restrict__ esrc, const float* __restrict__ dinv,
        const unsigned char* __restrict__ h1q, const float* __restrict__ b1,
        const ushort* __restrict__ Bp2, ushort* __restrict__ h2h) {
    int w = threadIdx.x >> 6, lane = threadIdx.x & 63;
    int v = blockIdx.x * 4 + w;              // grid 12500 -> v < 50000
    int q = lane >> 4, l = lane & 15;
    int beg = rowptr[v], d = deg[v];
    float dv = dinv[v];
    f32x2 zz; zz.x = 0.f; zz.y = 0.f;
    f32x2 aA[4] = {zz, zz, zz, zz};          // chain A: col pairs (l*8+2j, l*8+2j+1)
    f32x2 aB[4] = {zz, zz, zz, zz};          // chain B
    if (q == 0) {                            // self-loop counted once
        uint2 g = *(const uint2*)(h1q + (size_t)v * 128 + l * 8);
        float ws = dv * dv;
        f32x2 wv; wv.x = ws; wv.y = ws;
        aA[0] = pkfma(__builtin_amdgcn_cvt_pk_f32_fp8((int)g.x, false), wv, aA[0]);
        aA[1] = pkfma(__builtin_amdgcn_cvt_pk_f32_fp8((int)g.x, true),  wv, aA[1]);
        aA[2] = pkfma(__builtin_amdgcn_cvt_pk_f32_fp8((int)g.y, false), wv, aA[2]);
        aA[3] = pkfma(__builtin_amdgcn_cvt_pk_f32_fp8((int)g.y, true),  wv, aA[3]);
    }
    // own-lane edge: pack (f16 weight, src) once; loop shfls ONE word per edge
    int e_l = (lane < d) ? esrc[beg + lane] : 0;
    float wd = (lane < d) ? dinv[e_l] * dv : 0.f;   // 0: invalid edges vanish
    int up = (int)(((uint)f2h(wd) << 16) | (uint)e_l);
    int dm = min(d, 64);
    int i = 0;
    for (; i + 16 <= dm; i += 16) {          // 16 edges per iter, 4 loads in flight
        int u0 = __shfl(up, i + q, 64);
        int u1 = __shfl(up, i + 4 + q, 64);
        int u2 = __shfl(up, i + 8 + q, 64);
        int u3 = __shfl(up, i + 12 + q, 64);
        int s0 = u0 & 0xffff, s1 = u1 & 0xffff, s2 = u2 & 0xffff, s3 = u3 & 0xffff;
        float w0 = h2f_u((uint)u0 >> 16), w1 = h2f_u((uint)u1 >> 16);
        float w2 = h2f_u((uint)u2 >> 16), w3 = h2f_u((uint)u3 >> 16);
        uint2 g0 = *(const uint2*)(h1q + (size_t)s0 * 128 + l * 8);
        uint2 g1 = *(const uint2*)(h1q + (size_t)s1 * 128 + l * 8);
        uint2 g2 = *(const uint2*)(h1q + (size_t)s2 * 128 + l * 8);
        uint2 g3 = *(const uint2*)(h1q + (size_t)s3 * 128 + l * 8);
        f32x2 w0v; w0v.x = w0; w0v.y = w0;
        f32x2 w1v; w1v.x = w1; w1v.y = w1;
        f32x2 w2v; w2v.x = w2; w2v.y = w2;
        f32x2 w3v; w3v.x = w3; w3v.y = w3;
        aA[0] = pkfma(__builtin_amdgcn_cvt_pk_f32_fp8((int)g0.x, false), w0v, aA[0]);
        aA[1] = pkfma(__builtin_amdgcn_cvt_pk_f32_fp8((int)g0.x, true),  w0v, aA[1]);
        aA[2] = pkfma(__builtin_amdgcn_cvt_pk_f32_fp8((int)g0.y, false), w0v, aA[2]);
        aA[3] = pkfma(__builtin_amdgcn_cvt_pk_f32_fp8((int)g0.y, true),  w0v, aA[3]);
        aB[0] = pkfma(__builtin_amdgcn_cvt_pk_f32_fp8((int)g1.x, false), w1v, aB[0]);
        aB[1] = pkfma(__builtin_amdgcn_cvt_pk_f32_fp8((int)g1.x, true),  w1v, aB[1]);
        aB[2] = pkfma(__builtin_amdgcn_cvt_pk_f32_fp8((int)g1.y, false), w1v, aB[2]);
        aB[3] = pkfma(__builtin_amdgcn_cvt_pk_f32_fp8((int)g1.y, true),  w1v, aB[3]);
        aA[0] = pkfma(__builtin_amdgcn_cvt_pk_f32_fp8((int)g2.x, false), w2v, aA[0]);
        aA[1] = pkfma(__builtin_amdgcn_cvt_pk_f32_fp8((int)g2.x, true),  w2v, aA[1]);
        aA[2] = pkfma(__builtin_amdgcn_cvt_pk_f32_fp8((int)g2.y, false), w2v, aA[2]);
        aA[3] = pkfma(__builtin_amdgcn_cvt_pk_f32_fp8((int)g2.y, true),  w2v, aA[3]);
        aB[0] = pkfma(__builtin_amdgcn_cvt_pk_f32_fp8((int)g3.x, false), w3v, aB[0]);
        aB[1] = pkfma(__builtin_amdgcn_cvt_pk_f32_fp8((int)g3.x, true),  w3v, aB[1]);
        aB[2] = pkfma(__builtin_amdgcn_cvt_pk_f32_fp8((int)g3.y, false), w3v, aB[2]);
        aB[3] = pkfma(__builtin_amdgcn_cvt_pk_f32_fp8((int)g3.y, true),  w3v, aB[3]);
    }
    for (; i + 8 <= dm; i += 8) {            // 8 edges per iter
        int u0 = __shfl(up, i + q, 64);
        int u1 = __shfl(up, i + 4 + q, 64);
        int s0 = u0 & 0xffff, s1 = u1 & 0xffff;
        float w0 = h2f_u((uint)u0 >> 16), w1 = h2f_u((uint)u1 >> 16);
        uint2 g0 = *(const uint2*)(h1q + (size_t)s0 * 128 + l * 8);
        uint2 g1 = *(const uint2*)(h1q + (size_t)s1 * 128 + l * 8);
        f32x2 w0v; w0v.x = w0; w0v.y = w0;
        f32x2 w1v; w1v.x = w1; w1v.y = w1;
        aA[0] = pkfma(__builtin_amdgcn_cvt_pk_f32_fp8((int)g0.x, false), w0v, aA[0]);
        aA[1] = pkfma(__builtin_amdgcn_cvt_pk_f32_fp8((int)g0.x, true),  w0v, aA[1]);
        aA[2] = pkfma(__builtin_amdgcn_cvt_pk_f32_fp8((int)g0.y, false), w0v, aA[2]);
        aA[3] = pkfma(__builtin_amdgcn_cvt_pk_f32_fp8((int)g0.y, true),  w0v, aA[3]);
        aB[0] = pkfma(__builtin_amdgcn_cvt_pk_f32_fp8((int)g1.x, false), w1v, aB[0]);
        aB[1] = pkfma(__builtin_amdgcn_cvt_pk_f32_fp8((int)g1.x, true),  w1v, aB[1]);
        aB[2] = pkfma(__builtin_amdgcn_cvt_pk_f32_fp8((int)g1.y, false), w1v, aB[2]);
        aB[3] = pkfma(__builtin_amdgcn_cvt_pk_f32_fp8((int)g1.y, true),  w1v, aB[3]);
    }
    for (; i < dm; i += 4) {                 // tail: clamp shfl idx, zero weight
        int idx = i + q;
        int cl = idx & 63;
        int u0 = __shfl(up, cl, 64);
        int s0 = u0 & 0xffff;
        float w0 = (idx < dm) ? h2f_u((uint)u0 >> 16) : 0.f;
        uint2 g0 = *(const uint2*)(h1q + (size_t)s0 * 128 + l * 8);
        f32x2 w0v; w0v.x = w0; w0v.y = w0;
        aA[0] = pkfma(__builtin_amdgcn_cvt_pk_f32_fp8((int)g0.x, false), w0v, aA[0]);
        aA[1] = pkfma(__builtin_amdgcn_cvt_pk_f32_fp8((int)g0.x, true),  w0v, aA[1]);
        aA[2] = pkfma(__builtin_amdgcn_cvt_pk_f32_fp8((int)g0.y, false), w0v, aA[2]);
        aA[3] = pkfma(__builtin_amdgcn_cvt_pk_f32_fp8((int)g0.y, true),  w0v, aA[3]);
    }
    for (int j = 64 + q; j < d; j += 4) {    // rare deg>64 tail
        int s = esrc[beg + j];
        float g = dinv[s] * dv;
        uint2 gs = *(const uint2*)(h1q + (size_t)s * 128 + l * 8);
        f32x2 gv; gv.x = g; gv.y = g;
        aA[0] = pkfma(__builtin_amdgcn_cvt_pk_f32_fp8((int)gs.x, false), gv, aA[0]);
        aA[1] = pkfma(__builtin_amdgcn_cvt_pk_f32_fp8((int)gs.x, true),  gv, aA[1]);
        aA[2] = pkfma(__builtin_amdgcn_cvt_pk_f32_fp8((int)gs.y, false), gv, aA[2]);
        aA[3] = pkfma(__builtin_amdgcn_cvt_pk_f32_fp8((int)gs.y, true),  gv, aA[3]);
    }
    // combine chains (fp32 throughout)
    float a0 = aA[0].x + aB[0].x, a1 = aA[0].y + aB[0].y;
    float a2 = aA[1].x + aB[1].x, a3 = aA[1].y + aB[1].y;
    float a4 = aA[2].x + aB[2].x, a5 = aA[2].y + aB[2].y;
    float a6 = aA[3].x + aB[3].x, a7 = aA[3].y + aB[3].y;
    // fold quarters: butterfly -> ALL lanes hold the full sums for cols l*8..l*8+7
    a0 += __shfl_xor(a0, 16, 64); a0 += __shfl_xor(a0, 32, 64);
    a1 += __shfl_xor(a1, 16, 64); a1 += __shfl_xor(a1, 32, 64);
    a2 += __shfl_xor(a2, 16, 64); a2 += __shfl_xor(a2, 32, 64);
    a3 += __shfl_xor(a3, 16, 64); a3 += __shfl_xor(a3, 32, 64);
    a4 += __shfl_xor(a4, 16, 64); a4 += __shfl_xor(a4, 32, 64);
    a5 += __shfl_xor(a5, 16, 64); a5 += __shfl_xor(a5, 32, 64);
    a6 += __shfl_xor(a6, 16, 64); a6 += __shfl_xor(a6, 32, 64);
    a7 += __shfl_xor(a7, 16, 64); a7 += __shfl_xor(a7, 32, 64);
    // bias + relu on all lanes (needed for the A-frag shuffle below)
    float4 bb0 = ((const float4*)b1)[l * 2];
    float4 bb1 = ((const float4*)b1)[l * 2 + 1];
    a0 += bb0.x; a1 += bb0.y; a2 += bb0.z; a3 += bb0.w;
    a4 += bb1.x; a5 += bb1.y; a6 += bb1.z; a7 += bb1.w;
    a0 = a0 > 0.f ? a0 : 0.f;  a1 = a1 > 0.f ? a1 : 0.f;
    a2 = a2 > 0.f ? a2 : 0.f;  a3 = a3 > 0.f ? a3 : 0.f;
    a4 = a4 > 0.f ? a4 : 0.f;  a5 = a5 > 0.f ? a5 : 0.f;
    a6 = a6 > 0.f ? a6 : 0.f;  a7 = a7 > 0.f ? a7 : 0.f;
    // pack to f16 bits; lane holds halves k = l*8 .. l*8+7 of the h1-agg row
    uint pk0 = ((uint)f2h(a1) << 16) | (uint)f2h(a0);
    uint pk1 = ((uint)f2h(a3) << 16) | (uint)f2h(a2);
    uint pk2 = ((uint)f2h(a5) << 16) | (uint)f2h(a4);
    uint pk3 = ((uint)f2h(a7) << 16) | (uint)f2h(a6);
    // per-row GEMM2: A-frag lane needs k = kt*32 + q*8 + j  ->  source lane kt*4+q
    f32x4 acc[3] = {};
#pragma unroll
    for (int kt = 0; kt < 4; ++kt) {
        int srcl = kt * 4 + q;
        union { uint u[4]; half8 a; } ua;
        ua.u[0] = (uint)__shfl((int)pk0, srcl, 64);
        ua.u[1] = (uint)__shfl((int)pk1, srcl, 64);
        ua.u[2] = (uint)__shfl((int)pk2, srcl, 64);
        ua.u[3] = (uint)__shfl((int)pk3, srcl, 64);
#pragma unroll
        for (int nt = 0; nt < 3; ++nt) {
            half8 b = *(const half8*)(Bp2 + (((nt * 4 + kt) * 64) + lane) * 8);
            acc[nt] = __builtin_amdgcn_mfma_f32_16x16x32_f16(ua.a, b, acc[nt], 0, 0, 0);
        }
    }
    // broadcast-row MFMA: reg 0 of each quarter's acc holds col = nt*16 + l.
    if (q == 0) {
        h2h[(size_t)v * H2S + l] = f2h(acc[0][0]);
    } else if (q == 1) {
        h2h[(size_t)v * H2S + 16 + l] = f2h(acc[1][0]);
    } else if (q == 2 && l < 8) {
        h2h[(size_t)v * H2S + 32 + l] = f2h(acc[2][0]);
    }
}

// ---------------- layer-2 aggregation + bias + log_softmax (2 nodes/wave, 1 shfl/edge) ----------

__global__ __launch_bounds__(256) void agg2_lsm(
        const int* __restrict__ rowptr, const int* __restrict__ deg,
        const int* __restrict__ esrc, const float* __restrict__ dinv,
        const ushort* __restrict__ h2h, const float* __restrict__ b2,
        float* __restrict__ out) {
    int t = threadIdx.x;
    int w = t >> 6, lane = t & 63;
    int half = lane >> 5, l = lane & 31;
    int v = blockIdx.x * 8 + w * 2 + half;   // grid 6250 -> v < 50000 always
    int beg = rowptr[v], d = deg[v];
    float dv = dinv[v];
    __half2 z = __float2half2_rn(0.f);
    __half2 cA = z, cB = z;
    {   // self-loop (l<20 meaningful; rest discarded)
        uint hv = *(const uint*)(h2h + (size_t)v * H2S + l * 2);
        cA = __hfma2(u2h2(hv), __float2half2_rn(dv * dv), cA);
    }
    int e_l = (l < d) ? esrc[beg + l] : 0;
    float wd = (l < d) ? dinv[e_l] * dv : 0.f;
    int up = (int)(((uint)f2h(wd) << 16) | (uint)e_l);
    int dm = min(d, 32);
    int base = half * 32;
    int i = 0;
    for (; i + 8 <= dm; i += 8) {            // 8 edges per iter, 8 loads in flight
        int u0 = __shfl(up, base + i + 0, 64);
        int u1 = __shfl(up, base + i + 1, 64);
        int u2 = __shfl(up, base + i + 2, 64);
        int u3 = __shfl(up, base + i + 3, 64);
        int u4 = __shfl(up, base + i + 4, 64);
        int u5 = __shfl(up, base + i + 5, 64);
        int u6 = __shfl(up, base + i + 6, 64);
        int u7 = __shfl(up, base + i + 7, 64);
        uint h0 = *(const uint*)(h2h + (size_t)(u0 & 0xffff) * H2S + l * 2);
        uint h1 = *(const uint*)(h2h + (size_t)(u1 & 0xffff) * H2S + l * 2);
        uint h2 = *(const uint*)(h2h + (size_t)(u2 & 0xffff) * H2S + l * 2);
        uint h3 = *(const uint*)(h2h + (size_t)(u3 & 0xffff) * H2S + l * 2);
        uint h4 = *(const uint*)(h2h + (size_t)(u4 & 0xffff) * H2S + l * 2);
        uint h5 = *(const uint*)(h2h + (size_t)(u5 & 0xffff) * H2S + l * 2);
        uint h6 = *(const uint*)(h2h + (size_t)(u6 & 0xffff) * H2S + l * 2);
        uint h7 = *(const uint*)(h2h + (size_t)(u7 & 0xffff) * H2S + l * 2);
        cA = __hfma2(u2h2(h0), u2h2(wrep((uint)u0)), cA);
        cB = __hfma2(u2h2(h1), u2h2(wrep((uint)u1)), cB);
        cA = __hfma2(u2h2(h2), u2h2(wrep((uint)u2)), cA);
        cB = __hfma2(u2h2(h3), u2h2(wrep((uint)u3)), cB);
        cA = __hfma2(u2h2(h4), u2h2(wrep((uint)u4)), cA);
        cB = __hfma2(u2h2(h5), u2h2(wrep((uint)u5)), cB);
        cA = __hfma2(u2h2(h6), u2h2(wrep((uint)u6)), cA);
        cB = __hfma2(u2h2(h7), u2h2(wrep((uint)u7)), cB);
    }
    for (; i + 4 <= dm; i += 4) {
        int u0 = __shfl(up, base + i + 0, 64);
        int u1 = __shfl(up, base + i + 1, 64);
        int u2 = __shfl(up, base + i + 2, 64);
        int u3 = __shfl(up, base + i + 3, 64);
        uint h0 = *(const uint*)(h2h + (size_t)(u0 & 0xffff) * H2S + l * 2);
        uint h1 = *(const uint*)(h2h + (size_t)(u1 & 0xffff) * H2S + l * 2);
        uint h2 = *(const uint*)(h2h + (size_t)(u2 & 0xffff) * H2S + l * 2);
        uint h3 = *(const uint*)(h2h + (size_t)(u3 & 0xffff) * H2S + l * 2);
        cA = __hfma2(u2h2(h0), u2h2(wrep((uint)u0)), cA);
        cB = __hfma2(u2h2(h1), u2h2(wrep((uint)u1)), cB);
        cA = __hfma2(u2h2(h2), u2h2(wrep((uint)u2)), cA);
        cB = __hfma2(u2h2(h3), u2h2(wrep((uint)u3)), cB);
    }
    for (; i < dm; ++i) {
        int u0 = __shfl(up, base + i, 64);
        uint h0 = *(const uint*)(h2h + (size_t)(u0 & 0xffff) * H2S + l * 2);
        cA = __hfma2(u2h2(h0), u2h2(wrep((uint)u0)), cA);
    }
    for (i = 32; i < d; ++i) {               // rare deg>32 tail
        int s = esrc[beg + i];
        float g = dinv[s] * dv;
        uint hs = *(const uint*)(h2h + (size_t)s * H2S + l * 2);
        cA = __hfma2(u2h2(hs), __float2half2_rn(g), cA);
    }
    float2 fA = __half22float2(cA);
    float2 fB = __half22float2(cB);
    float ax = fA.x + fB.x, ay = fA.y + fB.y;
    if (l < 20) {
        float2 bb = ((const float2*)b2)[l];
        ax += bb.x; ay += bb.y;
    }
    float m = (l < 20) ? fmaxf(ax, ay) : -INFINITY;
#pragma unroll
    for (int off = 16; off; off >>= 1) m = fmaxf(m, __shfl_xor(m, off, 64));
    float e = (l < 20) ? (expf(ax - m) + expf(ay - m)) : 0.f;
#pragma unroll
    for (int off = 16; off; off >>= 1) e += __shfl_xor(e, off, 64);
    float ls = logf(e);
    if (l < 20) {
        float2 o;
        o.x = ax - m - ls;
        o.y = ay - m - ls;
        ((float2*)(out + (size_t)v * N_CLASSES))[l] = o;
    }
}

// ---------------- launch ----------------

extern "C" void kernel_launch(void* const* d_in, const int* in_sizes, int n_in,
                              void* d_out, int out_size, void* d_ws, size_t ws_size,
                              hipStream_t stream) {
    const float* x  = (const float*)d_in[0];
    const int*   ei = (const int*)d_in[1];
    const float* W1 = (const float*)d_in[2];
    const float* b1 = (const float*)d_in[3];
    const float* W2 = (const float*)d_in[4];
    const float* b2 = (const float*)d_in[5];
    const int* src = ei;
    const int* dst = ei + N_EDGES;
    float* out = (float*)d_out;

    char* ws = (char*)d_ws;
    size_t off = 0;
    auto alloc = [&](size_t bytes) {
        void* p = ws + off;
        off += (bytes + 255) & ~(size_t)255;
        return p;
    };
    int*    cursor = (int*)alloc((size_t)NBUCKET * 4);
    int*    deg    = (int*)alloc((size_t)N_NODES * 4);
    float*  dinv   = (float*)alloc((size_t)N_NODES * 4);
    int*    rowptr = (int*)alloc((size_t)N_NODES * 4);
    uint*   ebuf   = (uint*)alloc((size_t)NBUCKET * BCAP * 4);
    int*    esrc   = (int*)alloc((size_t)N_EDGES * 4);
    ushort* Bp1    = (ushort*)alloc((size_t)32768 * 2);
    ushort* Bp2    = (ushort*)alloc((size_t)6144 * 2);
    unsigned char* h1q = (unsigned char*)alloc((size_t)ROWS_PAD * 128);
    ushort* h2h    = (ushort*)alloc((size_t)ROWS_PAD * H2S * 2);

    // --- preprocessing: tiny memset + partition ---
    (void)hipMemsetAsync(cursor, 0, (size_t)NBUCKET * 4, stream);
    partition_repack<<<256, 256, 0, stream>>>(src, dst, cursor, ebuf, W1, Bp1, W2, Bp2);

    // --- fused CSR-build || GEMM1 (independent halves, co-scheduled) ---
    csr_gemm1<<<NBUCKET + G1_BLOCKS, 256, 0, stream>>>(
        ebuf, cursor, deg, dinv, rowptr, esrc, x, Bp1, h1q);

    // --- agg1 (fp8 gather) + per-row GEMM2 fused ---
    agg1_w2<<<N_NODES / 4, 256, 0, stream>>>(rowptr, deg, esrc, dinv, h1q, b1, Bp2, h2h);

    // --- agg2 + bias + log_softmax ---
    agg2_lsm<<<N_NODES / 8, 256, 0, stream>>>(rowptr, deg, esrc, dinv, h2h, b2, out);
}

// Round 5
// 177.187 us; speedup vs baseline: 1.0849x; 1.0849x over previous
//
#include <hip/hip_runtime.h>
#include <hip/hip_fp16.h>
#include <cstdint>

#define N_NODES 50000
#define N_EDGES 800000
#define N_FEAT 256
#define HIDDEN 128
#define N_CLASSES 40
#define NBUCKET 196         // dst >> 8
#define EPB 3125            // edges per partition block (256 * 3125 = 800000)
#define BCAP 8192           // bucket capacity in ebuf (max count ~4400)
#define ROWS_PAD 50048      // 782 * 64
#define G1_BLOCKS 782       // ROWS_PAD / 64
#define H2S 64              // h2 row stride (halves) = 128 B aligned rows
#define LROW 136            // agg1 LDS row stride in ushorts (272 B, 16B-aligned + bank skew)

typedef _Float16 half8 __attribute__((ext_vector_type(8)));
typedef __fp16 fp16x2 __attribute__((ext_vector_type(2)));
typedef __attribute__((ext_vector_type(4))) float f32x4;

__device__ inline ushort f2h(float f) {
    return __half_as_ushort(__float2half_rn(f));
}
__device__ inline __half2 u2h2(uint u) {
    union { uint u; __half2 h; } v; v.u = u; return v.h;
}
// replicate high half of u into both halves (weight rebuild after 1-word shfl)
__device__ inline uint wrep(uint u) {
    uint t = u >> 16;
    return (t << 16) | t;
}

// ---------------- 1) partition edges into fixed-capacity buckets + W1/W2 repack ----------------
// NO global per-node atomics (round-2 lesson: 800k random global atomicAdd = +26us).

__global__ __launch_bounds__(256) void partition_repack(
        const int* __restrict__ src, const int* __restrict__ dst,
        int* __restrict__ cursor, uint* __restrict__ ebuf,
        const float* __restrict__ W1, ushort* __restrict__ Bp1,
        const float* __restrict__ W2, ushort* __restrict__ Bp2) {
    __shared__ int h[NBUCKET];
    __shared__ int base[NBUCKET];
    __shared__ int cur[NBUCKET];
    int blk = blockIdx.x, t = threadIdx.x;
    int gid = blk * 256 + t;
    if (gid < 32768) {       // W1 repack into MFMA B-frag order (f16)
        int j = gid & 7, lane = (gid >> 3) & 63, kt = (gid >> 9) & 7, nt = gid >> 12;
        int k = kt * 32 + (lane >> 4) * 8 + j;
        int n = nt * 16 + (lane & 15);
        Bp1[gid] = f2h(W1[k * HIDDEN + n]);
    } else if (gid < 32768 + 6144) {   // W2 repack (3 nt * 4 kt * 64 * 8)
        int i2 = gid - 32768;
        int j = i2 & 7, lane = (i2 >> 3) & 63, kt = (i2 >> 9) & 3, nt = i2 >> 11;
        int k = kt * 32 + (lane >> 4) * 8 + j;
        int n = nt * 16 + (lane & 15);
        Bp2[i2] = (n < N_CLASSES) ? f2h(W2[k * N_CLASSES + n]) : (ushort)0;
    }
    if (t < NBUCKET) { h[t] = 0; cur[t] = 0; }
    __syncthreads();
    int eb = blk * EPB;
    for (int i = t; i < EPB; i += 256)
        atomicAdd(&h[dst[eb + i] >> 8], 1);
    __syncthreads();
    if (t < NBUCKET)
        base[t] = (h[t] > 0) ? atomicAdd(&cursor[t], h[t]) : 0;
    __syncthreads();
    for (int i = t; i < EPB; i += 256) {
        int d = dst[eb + i], sv = src[eb + i];
        int bk = d >> 8;
        int p = base[bk] + atomicAdd(&cur[bk], 1);
        ebuf[bk * BCAP + p] = ((uint)d << 16) | (uint)sv;
    }
}

// ---------------- 2) FUSED: bucket CSR build (blocks 0..195)  ||  GEMM1 (blocks 196..977) ----------

__global__ __launch_bounds__(256) void csr_gemm1(
        const uint* __restrict__ ebuf, const int* __restrict__ cursor,
        int* __restrict__ deg, float* __restrict__ dinv,
        int* __restrict__ rowptr, int* __restrict__ esrc,
        const float* __restrict__ x, const ushort* __restrict__ Bp,
        ushort* __restrict__ h1h) {
    if (blockIdx.x < NBUCKET) {
        // ----- per-bucket: degree + dinv + rowptr + CSR fill -----
        __shared__ int s[256];
        __shared__ int cnt[256];
        __shared__ int exc[256];
        __shared__ int cur[256];
        int b = blockIdx.x, t = threadIdx.x;
        s[t] = (t < NBUCKET) ? cursor[t] : 0;
        __syncthreads();
        for (int off = 1; off < 256; off <<= 1) {
            int t2 = 0;
            if (t >= off) t2 = s[t - off];
            __syncthreads();
            s[t] += t2;
            __syncthreads();
        }
        int beg = (b > 0) ? s[b - 1] : 0;      // CSR start of bucket b
        int ecnt = s[b] - beg;                 // edges in bucket b
        __syncthreads();
        cnt[t] = 0;
        cur[t] = 0;
        __syncthreads();
        const uint* eb = ebuf + (size_t)b * BCAP;
        for (int i = t; i < ecnt; i += 256)
            atomicAdd(&cnt[(eb[i] >> 16) & 255], 1);
        __syncthreads();
        int d = cnt[t];
        s[t] = d;
        __syncthreads();
        for (int off = 1; off < 256; off <<= 1) {
            int t2 = 0;
            if (t >= off) t2 = s[t - off];
            __syncthreads();
            s[t] += t2;
            __syncthreads();
        }
        exc[t] = s[t] - d;
        int node = b * 256 + t;
        if (node < N_NODES) {
            deg[node] = d;
            dinv[node] = rsqrtf((float)(d + 1));   // +1 self-loop
            rowptr[node] = beg + exc[t];
        }
        __syncthreads();
        for (int i = t; i < ecnt; i += 256) {
            uint u = eb[i];
            int dl = (int)(u >> 16) & 255;
            int pos = beg + exc[dl] + atomicAdd(&cur[dl], 1);
            esrc[pos] = (int)(u & 0xffffu);
        }
    } else {
        // ----- GEMM1: h1h[N,128] = f16(x[N,256]) @ W1  (MFMA f16, no LDS) -----
        int t = threadIdx.x;
        int lane = t & 63, w = t >> 6;
        int r = lane & 15, q = lane >> 4;
        int row0 = (blockIdx.x - NBUCKET) * 64;
        int arow = row0 + w * 16 + r;
        if (arow >= N_NODES) arow = N_NODES - 1;     // clamp: no fault, row discarded later
        const float* xrow = x + (size_t)arow * N_FEAT;
        f32x4 acc[8] = {};
        for (int kt = 0; kt < 8; ++kt) {
            float4 v0 = *(const float4*)(xrow + kt * 32 + q * 8);
            float4 v1 = *(const float4*)(xrow + kt * 32 + q * 8 + 4);
            union { fp16x2 p[4]; half8 a; } u;
            u.p[0] = __builtin_amdgcn_cvt_pkrtz(v0.x, v0.y);
            u.p[1] = __builtin_amdgcn_cvt_pkrtz(v0.z, v0.w);
            u.p[2] = __builtin_amdgcn_cvt_pkrtz(v1.x, v1.y);
            u.p[3] = __builtin_amdgcn_cvt_pkrtz(v1.z, v1.w);
#pragma unroll
            for (int nt = 0; nt < 8; ++nt) {
                half8 b = *(const half8*)(Bp + (((nt * 8 + kt) * 64) + lane) * 8);
                acc[nt] = __builtin_amdgcn_mfma_f32_16x16x32_f16(u.a, b, acc[nt], 0, 0, 0);
            }
        }
#pragma unroll
        for (int nt = 0; nt < 8; ++nt) {
            int col = nt * 16 + r;
#pragma unroll
            for (int reg = 0; reg < 4; ++reg) {
                int row = row0 + w * 16 + q * 4 + reg;
                if (row < N_NODES) h1h[(size_t)row * HIDDEN + col] = f2h(acc[nt][reg]);
            }
        }
    }
}

// ---------------- layer-1 aggregation: 16 nodes/block, quarter-wave per node ----------------
// Quarter (16 lanes x uint4) covers one full 256B h1 row -> NO butterfly fold.
// 16 agg rows staged in LDS; GEMM2 = ONE 16-row MFMA tile (12 MFMAs per 16 nodes,
// vs 12 per node before). Per-node epilogue VALU/DS cut ~5x; wave count 50k -> 12.5k.

__global__ __launch_bounds__(256) void agg1_w2(
        const int* __restrict__ rowptr, const int* __restrict__ deg,
        const int* __restrict__ esrc, const float* __restrict__ dinv,
        const ushort* __restrict__ h1h, const float* __restrict__ b1,
        const ushort* __restrict__ Bp2, ushort* __restrict__ h2h) {
    __shared__ ushort hag[16 * LROW];        // 16 rows x 272 B
    int t = threadIdx.x;
    int w = t >> 6, lane = t & 63;
    int q = lane >> 4, l15 = lane & 15;
    int n = w * 4 + q;                       // node slot 0..15
    int v = blockIdx.x * 16 + n;             // grid 3125 -> v < 50000 exactly
    int beg = rowptr[v], d = deg[v];
    float dv = dinv[v];
    __half2 z = __float2half2_rn(0.f);
    __half2 cA0 = z, cA1 = z, cA2 = z, cA3 = z;   // chain A (even edges)
    __half2 cB0 = z, cB1 = z, cB2 = z, cB3 = z;   // chain B (odd edges)
    {   // self-loop
        uint4 hv = *(const uint4*)(h1h + (size_t)v * HIDDEN + l15 * 8);
        __half2 gs = __float2half2_rn(dv * dv);
        cA0 = __hfma2(u2h2(hv.x), gs, cA0);
        cA1 = __hfma2(u2h2(hv.y), gs, cA1);
        cA2 = __hfma2(u2h2(hv.z), gs, cA2);
        cA3 = __hfma2(u2h2(hv.w), gs, cA3);
    }
    // wave-uniform chunk count = max degree over the wave's 4 nodes
    int dmx = max(d, __shfl_xor(d, 16, 64));
    dmx = max(dmx, __shfl_xor(dmx, 32, 64));
    int qb = lane & 48;                      // quarter base lane
    for (int c = 0; c < dmx; c += 16) {
        // pack (f16 weight, src) for this quarter's next 16 edges; invalid -> w=0
        int idx = c + l15;
        int e = (idx < d) ? esrc[beg + idx] : 0;
        float wd = (idx < d) ? dinv[e] * dv : 0.f;
        int up = (int)(((uint)f2h(wd) << 16) | (uint)e);
        int lim = min(dmx - c, 16);
        for (int j = 0; j < lim; j += 4) {   // 4 edges in flight (2 per chain)
            int u0 = __shfl(up, qb + j + 0, 64);
            int u1 = __shfl(up, qb + j + 1, 64);
            int u2 = __shfl(up, qb + j + 2, 64);
            int u3 = __shfl(up, qb + j + 3, 64);
            uint4 g0 = *(const uint4*)(h1h + (size_t)(u0 & 0xffff) * HIDDEN + l15 * 8);
            uint4 g1 = *(const uint4*)(h1h + (size_t)(u1 & 0xffff) * HIDDEN + l15 * 8);
            uint4 g2 = *(const uint4*)(h1h + (size_t)(u2 & 0xffff) * HIDDEN + l15 * 8);
            uint4 g3 = *(const uint4*)(h1h + (size_t)(u3 & 0xffff) * HIDDEN + l15 * 8);
            __half2 w0 = u2h2(wrep((uint)u0));
            __half2 w1 = u2h2(wrep((uint)u1));
            __half2 w2 = u2h2(wrep((uint)u2));
            __half2 w3 = u2h2(wrep((uint)u3));
            cA0 = __hfma2(u2h2(g0.x), w0, cA0);
            cA1 = __hfma2(u2h2(g0.y), w0, cA1);
            cA2 = __hfma2(u2h2(g0.z), w0, cA2);
            cA3 = __hfma2(u2h2(g0.w), w0, cA3);
            cB0 = __hfma2(u2h2(g1.x), w1, cB0);
            cB1 = __hfma2(u2h2(g1.y), w1, cB1);
            cB2 = __hfma2(u2h2(g1.z), w1, cB2);
            cB3 = __hfma2(u2h2(g1.w), w1, cB3);
            cA0 = __hfma2(u2h2(g2.x), w2, cA0);
            cA1 = __hfma2(u2h2(g2.y), w2, cA1);
            cA2 = __hfma2(u2h2(g2.z), w2, cA2);
            cA3 = __hfma2(u2h2(g2.w), w2, cA3);
            cB0 = __hfma2(u2h2(g3.x), w3, cB0);
            cB1 = __hfma2(u2h2(g3.y), w3, cB1);
            cB2 = __hfma2(u2h2(g3.z), w3, cB2);
            cB3 = __hfma2(u2h2(g3.w), w3, cB3);
        }
    }
    // combine chains in fp32, bias + relu (quarter owns full row: NO fold)
    float2 fA0 = __half22float2(cA0), fB0 = __half22float2(cB0);
    float2 fA1 = __half22float2(cA1), fB1 = __half22float2(cB1);
    float2 fA2 = __half22float2(cA2), fB2 = __half22float2(cB2);
    float2 fA3 = __half22float2(cA3), fB3 = __half22float2(cB3);
    float a0 = fA0.x + fB0.x, a1 = fA0.y + fB0.y;
    float a2 = fA1.x + fB1.x, a3 = fA1.y + fB1.y;
    float a4 = fA2.x + fB2.x, a5 = fA2.y + fB2.y;
    float a6 = fA3.x + fB3.x, a7 = fA3.y + fB3.y;
    float4 bb0 = ((const float4*)b1)[l15 * 2];
    float4 bb1 = ((const float4*)b1)[l15 * 2 + 1];
    a0 += bb0.x; a1 += bb0.y; a2 += bb0.z; a3 += bb0.w;
    a4 += bb1.x; a5 += bb1.y; a6 += bb1.z; a7 += bb1.w;
    a0 = a0 > 0.f ? a0 : 0.f;  a1 = a1 > 0.f ? a1 : 0.f;
    a2 = a2 > 0.f ? a2 : 0.f;  a3 = a3 > 0.f ? a3 : 0.f;
    a4 = a4 > 0.f ? a4 : 0.f;  a5 = a5 > 0.f ? a5 : 0.f;
    a6 = a6 > 0.f ? a6 : 0.f;  a7 = a7 > 0.f ? a7 : 0.f;
    uint4 ov;
    ov.x = ((uint)f2h(a1) << 16) | (uint)f2h(a0);
    ov.y = ((uint)f2h(a3) << 16) | (uint)f2h(a2);
    ov.z = ((uint)f2h(a5) << 16) | (uint)f2h(a4);
    ov.w = ((uint)f2h(a7) << 16) | (uint)f2h(a6);
    *(uint4*)(&hag[n * LROW + l15 * 8]) = ov;    // 16B aligned (LROW*2=272, l15*16)
    __syncthreads();
    // GEMM2: one 16x128 A-tile x Bp2 -> 16 nodes x 40 cols. Waves 0..2 each do one nt.
    if (w < 3) {
        int r = lane & 15;                   // output col within tile / A row
        f32x4 acc = {};
#pragma unroll
        for (int kt = 0; kt < 4; ++kt) {
            half8 a = *(const half8*)(&hag[r * LROW + kt * 32 + q * 8]);
            half8 b = *(const half8*)(Bp2 + (((w * 4 + kt) * 64) + lane) * 8);
            acc = __builtin_amdgcn_mfma_f32_16x16x32_f16(a, b, acc, 0, 0, 0);
        }
        int col = w * 16 + r;
        if (col < N_CLASSES) {
            int vb = blockIdx.x * 16 + q * 4;
#pragma unroll
            for (int reg = 0; reg < 4; ++reg)
                h2h[(size_t)(vb + reg) * H2S + col] = f2h(acc[reg]);
        }
    }
}

// ---------------- layer-2 aggregation + bias + log_softmax (2 nodes/wave, 1 shfl/edge) ----------

__global__ __launch_bounds__(256) void agg2_lsm(
        const int* __restrict__ rowptr, const int* __restrict__ deg,
        const int* __restrict__ esrc, const float* __restrict__ dinv,
        const ushort* __restrict__ h2h, const float* __restrict__ b2,
        float* __restrict__ out) {
    int t = threadIdx.x;
    int w = t >> 6, lane = t & 63;
    int half = lane >> 5, l = lane & 31;
    int v = blockIdx.x * 8 + w * 2 + half;   // grid 6250 -> v < 50000 always
    int beg = rowptr[v], d = deg[v];
    float dv = dinv[v];
    __half2 z = __float2half2_rn(0.f);
    __half2 cA = z, cB = z;
    {   // self-loop (l<20 meaningful; rest discarded)
        uint hv = *(const uint*)(h2h + (size_t)v * H2S + l * 2);
        cA = __hfma2(u2h2(hv), __float2half2_rn(dv * dv), cA);
    }
    int e_l = (l < d) ? esrc[beg + l] : 0;
    float wd = (l < d) ? dinv[e_l] * dv : 0.f;
    int up = (int)(((uint)f2h(wd) << 16) | (uint)e_l);
    int dm = min(d, 32);
    int base = half * 32;
    int i = 0;
    for (; i + 8 <= dm; i += 8) {            // 8 edges per iter, 8 loads in flight
        int u0 = __shfl(up, base + i + 0, 64);
        int u1 = __shfl(up, base + i + 1, 64);
        int u2 = __shfl(up, base + i + 2, 64);
        int u3 = __shfl(up, base + i + 3, 64);
        int u4 = __shfl(up, base + i + 4, 64);
        int u5 = __shfl(up, base + i + 5, 64);
        int u6 = __shfl(up, base + i + 6, 64);
        int u7 = __shfl(up, base + i + 7, 64);
        uint h0 = *(const uint*)(h2h + (size_t)(u0 & 0xffff) * H2S + l * 2);
        uint h1 = *(const uint*)(h2h + (size_t)(u1 & 0xffff) * H2S + l * 2);
        uint h2 = *(const uint*)(h2h + (size_t)(u2 & 0xffff) * H2S + l * 2);
        uint h3 = *(const uint*)(h2h + (size_t)(u3 & 0xffff) * H2S + l * 2);
        uint h4 = *(const uint*)(h2h + (size_t)(u4 & 0xffff) * H2S + l * 2);
        uint h5 = *(const uint*)(h2h + (size_t)(u5 & 0xffff) * H2S + l * 2);
        uint h6 = *(const uint*)(h2h + (size_t)(u6 & 0xffff) * H2S + l * 2);
        uint h7 = *(const uint*)(h2h + (size_t)(u7 & 0xffff) * H2S + l * 2);
        cA = __hfma2(u2h2(h0), u2h2(wrep((uint)u0)), cA);
        cB = __hfma2(u2h2(h1), u2h2(wrep((uint)u1)), cB);
        cA = __hfma2(u2h2(h2), u2h2(wrep((uint)u2)), cA);
        cB = __hfma2(u2h2(h3), u2h2(wrep((uint)u3)), cB);
        cA = __hfma2(u2h2(h4), u2h2(wrep((uint)u4)), cA);
        cB = __hfma2(u2h2(h5), u2h2(wrep((uint)u5)), cB);
        cA = __hfma2(u2h2(h6), u2h2(wrep((uint)u6)), cA);
        cB = __hfma2(u2h2(h7), u2h2(wrep((uint)u7)), cB);
    }
    for (; i + 4 <= dm; i += 4) {
        int u0 = __shfl(up, base + i + 0, 64);
        int u1 = __shfl(up, base + i + 1, 64);
        int u2 = __shfl(up, base + i + 2, 64);
        int u3 = __shfl(up, base + i + 3, 64);
        uint h0 = *(const uint*)(h2h + (size_t)(u0 & 0xffff) * H2S + l * 2);
        uint h1 = *(const uint*)(h2h + (size_t)(u1 & 0xffff) * H2S + l * 2);
        uint h2 = *(const uint*)(h2h + (size_t)(u2 & 0xffff) * H2S + l * 2);
        uint h3 = *(const uint*)(h2h + (size_t)(u3 & 0xffff) * H2S + l * 2);
        cA = __hfma2(u2h2(h0), u2h2(wrep((uint)u0)), cA);
        cB = __hfma2(u2h2(h1), u2h2(wrep((uint)u1)), cB);
        cA = __hfma2(u2h2(h2), u2h2(wrep((uint)u2)), cA);
        cB = __hfma2(u2h2(h3), u2h2(wrep((uint)u3)), cB);
    }
    for (; i < dm; ++i) {
        int u0 = __shfl(up, base + i, 64);
        uint h0 = *(const uint*)(h2h + (size_t)(u0 & 0xffff) * H2S + l * 2);
        cA = __hfma2(u2h2(h0), u2h2(wrep((uint)u0)), cA);
    }
    for (i = 32; i < d; ++i) {               // rare deg>32 tail
        int s = esrc[beg + i];
        float g = dinv[s] * dv;
        uint hs = *(const uint*)(h2h + (size_t)s * H2S + l * 2);
        cA = __hfma2(u2h2(hs), __float2half2_rn(g), cA);
    }
    float2 fA = __half22float2(cA);
    float2 fB = __half22float2(cB);
    float ax = fA.x + fB.x, ay = fA.y + fB.y;
    if (l < 20) {
        float2 bb = ((const float2*)b2)[l];
        ax += bb.x; ay += bb.y;
    }
    float m = (l < 20) ? fmaxf(ax, ay) : -INFINITY;
#pragma unroll
    for (int off = 16; off; off >>= 1) m = fmaxf(m, __shfl_xor(m, off, 64));
    float e = (l < 20) ? (expf(ax - m) + expf(ay - m)) : 0.f;
#pragma unroll
    for (int off = 16; off; off >>= 1) e += __shfl_xor(e, off, 64);
    float ls = logf(e);
    if (l < 20) {
        float2 o;
        o.x = ax - m - ls;
        o.y = ay - m - ls;
        ((float2*)(out + (size_t)v * N_CLASSES))[l] = o;
    }
}

// ---------------- launch ----------------

extern "C" void kernel_launch(void* const* d_in, const int* in_sizes, int n_in,
                              void* d_out, int out_size, void* d_ws, size_t ws_size,
                              hipStream_t stream) {
    const float* x  = (const float*)d_in[0];
    const int*   ei = (const int*)d_in[1];
    const float* W1 = (const float*)d_in[2];
    const float* b1 = (const float*)d_in[3];
    const float* W2 = (const float*)d_in[4];
    const float* b2 = (const float*)d_in[5];
    const int* src = ei;
    const int* dst = ei + N_EDGES;
    float* out = (float*)d_out;

    char* ws = (char*)d_ws;
    size_t off = 0;
    auto alloc = [&](size_t bytes) {
        void* p = ws + off;
        off += (bytes + 255) & ~(size_t)255;
        return p;
    };
    int*    cursor = (int*)alloc((size_t)NBUCKET * 4);
    int*    deg    = (int*)alloc((size_t)N_NODES * 4);
    float*  dinv   = (float*)alloc((size_t)N_NODES * 4);
    int*    rowptr = (int*)alloc((size_t)N_NODES * 4);
    uint*   ebuf   = (uint*)alloc((size_t)NBUCKET * BCAP * 4);
    int*    esrc   = (int*)alloc((size_t)N_EDGES * 4);
    ushort* Bp1    = (ushort*)alloc((size_t)32768 * 2);
    ushort* Bp2    = (ushort*)alloc((size_t)6144 * 2);
    ushort* h1h    = (ushort*)alloc((size_t)ROWS_PAD * HIDDEN * 2);
    ushort* h2h    = (ushort*)alloc((size_t)ROWS_PAD * H2S * 2);

    // --- preprocessing: tiny memset + partition ---
    (void)hipMemsetAsync(cursor, 0, (size_t)NBUCKET * 4, stream);
    partition_repack<<<256, 256, 0, stream>>>(src, dst, cursor, ebuf, W1, Bp1, W2, Bp2);

    // --- fused CSR-build || GEMM1 (independent halves, co-scheduled) ---
    csr_gemm1<<<NBUCKET + G1_BLOCKS, 256, 0, stream>>>(
        ebuf, cursor, deg, dinv, rowptr, esrc, x, Bp1, h1h);

    // --- agg1 (16 nodes/block, LDS-staged tile GEMM2) ---
    agg1_w2<<<N_NODES / 16, 256, 0, stream>>>(rowptr, deg, esrc, dinv, h1h, b1, Bp2, h2h);

    // --- agg2 + bias + log_softmax ---
    agg2_lsm<<<N_NODES / 8, 256, 0, stream>>>(rowptr, deg, esrc, dinv, h2h, b2, out);
}